// Round 6
// baseline (382.926 us; speedup 1.0000x reference)
//
#include <hip/hip_runtime.h>
#include <hip/hip_bf16.h>
#include <math.h>

typedef unsigned short u16;
typedef unsigned int u32;
typedef __attribute__((ext_vector_type(4))) float f32x4;
typedef __attribute__((ext_vector_type(4))) short bf16x4;
typedef __attribute__((ext_vector_type(8))) short bf16x8;
typedef __attribute__((ext_vector_type(8))) unsigned short u16x8;

constexpr int Bc = 2, Sc = 2048, Dc = 1024, Hc = 16, DKc = 64, Mc = 4096;

__device__ __forceinline__ u16 f2bf(float f) {
  __hip_bfloat16 h = __float2bfloat16(f);      // RNE, hw v_cvt (pairs to cvt_pk)
  return __builtin_bit_cast(u16, h);
}

__device__ __forceinline__ void gll16(const u16* g, const u16* l) {
  __builtin_amdgcn_global_load_lds((const __attribute__((address_space(1))) void*)g,
                                   (__attribute__((address_space(3))) void*)l, 16, 0, 0);
}

// ---------------------------------------------------------------------------
// LDS tiles are [R rows][64 cols] u16 (128-B rows). XOR swizzle on 16-B slots:
// u16 index ^= ((row & 7) << 3); source side pre-swizzled for global_load_lds
// (rule #21: both-sides-or-neither).
// ---------------------------------------------------------------------------
__device__ __forceinline__ bf16x8 frag_swz(const u16* tile, int row, int col) {
  const int sw = (row & 7) << 3;
  const int base = row * 64 + col;
  bf16x4 lo = *(const bf16x4*)(tile + (base ^ sw));
  bf16x4 hi = *(const bf16x4*)(tile + ((base + 16) ^ sw));
  return __builtin_shufflevector(lo, hi, 0, 1, 2, 3, 4, 5, 6, 7);
}

// ---------------------------------------------------------------------------
__global__ __launch_bounds__(256) void cast_many(
    const float* __restrict__ i0, const float* __restrict__ i1,
    const float* __restrict__ i2, const float* __restrict__ i3,
    u16* __restrict__ o0, u16* __restrict__ o1,
    u16* __restrict__ o2, u16* __restrict__ o3, int n8)
{
  const int z = blockIdx.y;
  const float* in = z == 0 ? i0 : z == 1 ? i1 : z == 2 ? i2 : i3;
  u16* out = z == 0 ? o0 : z == 1 ? o1 : z == 2 ? o2 : o3;
  const int i = blockIdx.x * 256 + threadIdx.x;
  if (i >= n8) return;
  const float4* p = (const float4*)in + (size_t)i * 2;
  const float4 a = p[0], b = p[1];
  u16x8 o;
  o[0] = f2bf(a.x); o[1] = f2bf(a.y); o[2] = f2bf(a.z); o[3] = f2bf(a.w);
  o[4] = f2bf(b.x); o[5] = f2bf(b.y); o[6] = f2bf(b.z); o[7] = f2bf(b.w);
  ((u16x8*)out)[i] = o;
}

// ---------------------------------------------------------------------------
// gemm_core: acc = X[row0:+128] @ W[col0:+128]^T (bf16, BK=64, 512 thr, 4x2
// wave grid, wave tile 32x64, swizzled LDS, global_load_lds dbuf)
// ---------------------------------------------------------------------------
__device__ __forceinline__ void gemm_core(
    const u16* __restrict__ X, const u16* __restrict__ W,
    u16* smem, int row0, int col0, f32x4 (&acc)[2][4])
{
  const int tid = threadIdx.x;
  const int w = tid >> 6, lane = tid & 63;
  const int l15 = lane & 15, l4 = lane >> 4;
  const int wr = w >> 1, wc = w & 1;

  auto stage = [&](int buf, int k0) {
    u16* dA = smem + buf * 8192;
    u16* dB = smem + 16384 + buf * 8192;
#pragma unroll
    for (int s = 0; s < 2; ++s) {
      const int c = s * 512 + w * 64 + lane;
      const int r = c >> 3;
      const int cc = (c & 7) ^ (r & 7);          // pre-swizzled source slot
      gll16(X + (size_t)(row0 + r) * Dc + k0 + cc * 8, dA + (s * 512 + w * 64) * 8);
      gll16(W + (size_t)(col0 + r) * Dc + k0 + cc * 8, dB + (s * 512 + w * 64) * 8);
    }
  };

  stage(0, 0);
  __syncthreads();

  for (int kt = 0; kt < Dc / 64; ++kt) {
    const int cur = kt & 1;
    if (kt + 1 < Dc / 64) stage(cur ^ 1, (kt + 1) * 64);
    const u16* At = smem + cur * 8192;
    const u16* Bt = smem + 16384 + cur * 8192;
#pragma unroll
    for (int ks = 0; ks < 2; ++ks) {
      bf16x8 af[2], bfr[4];
#pragma unroll
      for (int m = 0; m < 2; ++m)
        af[m] = frag_swz(At, wr * 32 + m * 16 + l15, ks * 32 + l4 * 4);
#pragma unroll
      for (int n = 0; n < 4; ++n)
        bfr[n] = frag_swz(Bt, wc * 64 + n * 16 + l15, ks * 32 + l4 * 4);
#pragma unroll
      for (int m = 0; m < 2; ++m)
#pragma unroll
        for (int n = 0; n < 4; ++n)
          acc[m][n] = __builtin_amdgcn_mfma_f32_16x16x32_bf16(af[m], bfr[n], acc[m][n], 0, 0, 0);
    }
    __syncthreads();
  }
}

// ---------------------------------------------------------------------------
// gemm_qkv: fused Q/K/V projections (blockIdx.z). z=0,1 -> RoPE -> [B,H,S,DK];
// z=2 -> V transposed -> [B,H,DK,S].
// ---------------------------------------------------------------------------
__global__ __launch_bounds__(512) void gemm_qkv(
    const u16* __restrict__ xq, const u16* __restrict__ xk, const u16* __restrict__ xv,
    const u16* __restrict__ wq, const u16* __restrict__ wk, const u16* __restrict__ wv,
    const float* __restrict__ bq, const float* __restrict__ bk, const float* __restrict__ bv,
    u16* __restrict__ Qb, u16* __restrict__ Kb, u16* __restrict__ Vt)
{
  __shared__ u16 smem[4 * 128 * 64];             // 64 KB
  const int z = blockIdx.z;
  const u16* X = z == 0 ? xq : z == 1 ? xk : xv;
  const u16* W = z == 0 ? wq : z == 1 ? wk : wv;
  const float* bias = z == 0 ? bq : z == 1 ? bk : bv;

  const int tid = threadIdx.x;
  const int w = tid >> 6, lane = tid & 63;
  const int l15 = lane & 15, l4 = lane >> 4;
  const int wr = w >> 1, wc = w & 1;
  const int row0 = blockIdx.x * 128;
  const int col0 = blockIdx.y * 128;

  f32x4 acc[2][4] = {};
  gemm_core(X, W, smem, row0, col0, acc);

  if (z < 2) {                                   // Q or K: +bias, RoPE
    u16* Out = z == 0 ? Qb : Kb;
    const int h = (col0 >> 6) + wc;
#pragma unroll
    for (int m = 0; m < 2; ++m)
#pragma unroll
      for (int i = 0; i < 4; ++i) {
        const int row = row0 + wr * 32 + m * 16 + 4 * l4 + i;
        const int srow = row & (Sc - 1);
        const size_t obase = ((size_t)((row >> 11) * Hc + h) * Sc + srow) * DKc;
        float vv[4];
#pragma unroll
        for (int n = 0; n < 4; ++n)
          vv[n] = acc[m][n][i] + bias[col0 + wc * 64 + n * 16 + l15];
        float cs[2], sn[2];
#pragma unroll
        for (int hf = 0; hf < 2; ++hf) {
          const int jj = hf * 16 + l15;          // dk & 31
          const float ang = (float)srow * exp2f((float)jj * (-13.287712379549449f / 32.0f));
          sincosf(ang, &sn[hf], &cs[hf]);        // sin FIRST
        }
#pragma unroll
        for (int n = 0; n < 4; ++n) {
          const float rot = (n < 2) ? -vv[n ^ 2] : vv[n ^ 2];   // partner dk^32
          const float o = vv[n] * cs[n & 1] + rot * sn[n & 1];
          Out[obase + n * 16 + l15] = f2bf(o);
        }
      }
  } else {                                       // V -> [B,H,DK,S] via LDS transpose
    u16* T = smem;                               // [128 c][132 r]
    __syncthreads();
#pragma unroll
    for (int m = 0; m < 2; ++m)
#pragma unroll
      for (int i = 0; i < 4; ++i) {
        const int r = wr * 32 + m * 16 + 4 * l4 + i;
#pragma unroll
        for (int n = 0; n < 4; ++n) {
          const int c = wc * 64 + n * 16 + l15;
          T[c * 132 + r] = f2bf(acc[m][n][i] + bias[col0 + c]);
        }
      }
    __syncthreads();
    const int bidx = row0 >> 11, srow0 = row0 & (Sc - 1);
    const int c = tid >> 2, rq = (tid & 3) * 32;
    const int h = (col0 >> 6) + (c >> 6);
    const int dk = c & 63;
    u16* gdst = Vt + ((size_t)(bidx * Hc + h) * DKc + dk) * Sc + srow0 + rq;
#pragma unroll
    for (int u = 0; u < 4; ++u)
      *(u16x8*)(gdst + u * 8) = *(const u16x8*)&T[c * 132 + rq + u * 8];
  }
}

// ---------------------------------------------------------------------------
__global__ __launch_bounds__(512) void gemm_out(
    const u16* __restrict__ X, const u16* __restrict__ W,
    const float* __restrict__ bias, float* __restrict__ Out)
{
  __shared__ u16 smem[4 * 128 * 64];
  const int tid = threadIdx.x;
  const int w = tid >> 6, lane = tid & 63;
  const int l15 = lane & 15, l4 = lane >> 4;
  const int wr = w >> 1, wc = w & 1;
  const int row0 = blockIdx.x * 128;
  const int col0 = blockIdx.y * 128;

  f32x4 acc[2][4] = {};
  gemm_core(X, W, smem, row0, col0, acc);

#pragma unroll
  for (int m = 0; m < 2; ++m)
#pragma unroll
    for (int i = 0; i < 4; ++i) {
      const int row = row0 + wr * 32 + m * 16 + 4 * l4 + i;
#pragma unroll
      for (int n = 0; n < 4; ++n) {
        const int col = col0 + wc * 64 + n * 16 + l15;
        Out[(size_t)row * Dc + col] = acc[m][n][i] + bias[col];
      }
    }
}

// ---------------------------------------------------------------------------
// attn_mfma: causal flash attention, swapped-QK^T in-register softmax.
// QBLK=128 (4 waves x 32 q-rows), KVBLK=64, dbuf K/V staging, swizzled LDS.
// S^T = mfma(K_frag, Q_frag): thread holds S^T[k=n*16+4*l4+i][q=m*16+l15]
// -> row softmax = 15 local ops + 2 shuffles; P^T regs feed PV's A-operand
// directly (n=2ks+(j>>2), i=j&3). No P LDS round-trip.
// O/corr live on q=m*16+4*l4+i rows -> 4-way lane transpose via __shfl.
// ---------------------------------------------------------------------------
__global__ __launch_bounds__(256, 3) void attn_mfma(
    const u16* __restrict__ Qb, const u16* __restrict__ Kb,
    const u16* __restrict__ Vt, u16* __restrict__ Xb)
{
  __shared__ u16 smem[24576];                    // 48 KB
  // Qs [128][64] @0; K bufs @8192+buf*4096; V bufs @16384+buf*4096
  u16* Qs = smem;

  const int tid = threadIdx.x;
  const int w = tid >> 6, lane = tid & 63;
  const int l15 = lane & 15, l4 = lane >> 4;
  const int qt = gridDim.x - 1 - blockIdx.x;     // heavy q-tiles first
  const int bh = blockIdx.y;
  const int q0 = qt * 128;
  const u16* Qg = Qb + ((size_t)bh * Sc + q0) * DKc;
  const u16* Kg = Kb + (size_t)bh * Sc * DKc;
  const u16* Vg = Vt + (size_t)bh * DKc * Sc;

  // stage Q (swizzled source)
#pragma unroll
  for (int s = 0; s < 4; ++s) {
    const int c = s * 256 + w * 64 + lane;
    const int r = c >> 3;
    const int cc = (c & 7) ^ (r & 7);
    gll16(Qg + (size_t)r * DKc + cc * 8, Qs + (s * 256 + w * 64) * 8);
  }
  auto stageKV = [&](int buf, int k0) {
    u16* Kd = smem + 8192 + buf * 4096;
    u16* Vd = smem + 16384 + buf * 4096;
#pragma unroll
    for (int s = 0; s < 2; ++s) {
      const int c = s * 256 + w * 64 + lane;
      const int r = c >> 3;
      const int cc = (c & 7) ^ (r & 7);
      gll16(Kg + (size_t)(k0 + r) * DKc + cc * 8, Kd + (s * 256 + w * 64) * 8);
      gll16(Vg + (size_t)r * Sc + k0 + cc * 8,   Vd + (s * 256 + w * 64) * 8);
    }
  };
  stageKV(0, 0);
  __syncthreads();

  // hoist Q fragments (reused across all k-tiles)
  bf16x8 aq[2][2];
#pragma unroll
  for (int m = 0; m < 2; ++m)
#pragma unroll
    for (int ks = 0; ks < 2; ++ks)
      aq[m][ks] = frag_swz(Qs, w * 32 + m * 16 + l15, ks * 32 + l4 * 4);

  f32x4 aco[2][4] = {};
  float mreg[2], lreg[2];
#pragma unroll
  for (int m = 0; m < 2; ++m) { mreg[m] = -INFINITY; lreg[m] = 0.f; }

  const int nk = 2 * qt + 2;
  for (int kt = 0; kt < nk; ++kt) {
    const int cur = kt & 1;
    if (kt + 1 < nk) stageKV(cur ^ 1, (kt + 1) * 64);
    const u16* Kt = smem + 8192 + cur * 4096;
    const u16* Vc = smem + 16384 + cur * 4096;

    // S^T = K Q^T : acs[m][n][i] = S[q=m*16+l15][k=n*16+4*l4+i]
    f32x4 acs[2][4] = {};
#pragma unroll
    for (int ks = 0; ks < 2; ++ks) {
      bf16x8 bk[4];
#pragma unroll
      for (int n = 0; n < 4; ++n)
        bk[n] = frag_swz(Kt, n * 16 + l15, ks * 32 + l4 * 4);
#pragma unroll
      for (int m = 0; m < 2; ++m)
#pragma unroll
        for (int n = 0; n < 4; ++n)
          acs[m][n] = __builtin_amdgcn_mfma_f32_16x16x32_bf16(bk[n], aq[m][ks], acs[m][n], 0, 0, 0);
    }

    // in-register online softmax (q lane-local)
    const bool mtile = (kt >= 2 * qt);
    const int k0 = kt * 64;
    float corr[2];
#pragma unroll
    for (int m = 0; m < 2; ++m) {
      const int q = q0 + w * 32 + m * 16 + l15;
      float rm = -INFINITY;
#pragma unroll
      for (int n = 0; n < 4; ++n)
#pragma unroll
        for (int i = 0; i < 4; ++i) {
          float s = acs[m][n][i] * 0.125f;
          if (mtile && (k0 + n * 16 + 4 * l4 + i) > q) s = -1e9f;
          acs[m][n][i] = s;
          rm = fmaxf(rm, s);
        }
      rm = fmaxf(rm, __shfl_xor(rm, 16, 64));
      rm = fmaxf(rm, __shfl_xor(rm, 32, 64));
      const float mnew = fmaxf(mreg[m], rm);
      corr[m] = __expf(mreg[m] - mnew);
      mreg[m] = mnew;
      float rs = 0.f;
#pragma unroll
      for (int n = 0; n < 4; ++n)
#pragma unroll
        for (int i = 0; i < 4; ++i) {
          const float p = __expf(acs[m][n][i] - mnew);
          acs[m][n][i] = p;
          rs += p;
        }
      rs += __shfl_xor(rs, 16, 64);
      rs += __shfl_xor(rs, 32, 64);
      lreg[m] = lreg[m] * corr[m] + rs;
    }

    // rescale O (rows q=m*16+4*l4+i): fetch corr via lane transpose
#pragma unroll
    for (int m = 0; m < 2; ++m)
#pragma unroll
      for (int i = 0; i < 4; ++i) {
        const float c = __shfl(corr[m], 4 * l4 + i, 64);
#pragma unroll
        for (int n = 0; n < 4; ++n) aco[m][n][i] *= c;
      }

    // pack P^T regs -> PV A-frags (exact layout match)
    bf16x8 pa[2][2];
#pragma unroll
    for (int m = 0; m < 2; ++m)
#pragma unroll
      for (int ks = 0; ks < 2; ++ks) {
        bf16x8 t;
#pragma unroll
        for (int j = 0; j < 8; ++j)
          t[j] = (short)f2bf(acs[m][ks * 2 + (j >> 2)][j & 3]);
        pa[m][ks] = t;
      }

    // O += P V
#pragma unroll
    for (int ks = 0; ks < 2; ++ks) {
      bf16x8 bv[4];
#pragma unroll
      for (int n = 0; n < 4; ++n)
        bv[n] = frag_swz(Vc, n * 16 + l15, ks * 32 + l4 * 4);
#pragma unroll
      for (int m = 0; m < 2; ++m)
#pragma unroll
        for (int n = 0; n < 4; ++n)
          aco[m][n] = __builtin_amdgcn_mfma_f32_16x16x32_bf16(pa[m][ks], bv[n], aco[m][n], 0, 0, 0);
    }
    __syncthreads();
  }

  // epilogue: x[b, q, h*64+dk] = O/l (1/l via lane transpose)
  const int bidx = bh >> 4, h = bh & 15;
  float invl[2];
#pragma unroll
  for (int m = 0; m < 2; ++m) invl[m] = 1.0f / lreg[m];
#pragma unroll
  for (int m = 0; m < 2; ++m)
#pragma unroll
    for (int i = 0; i < 4; ++i) {
      const int q = q0 + w * 32 + m * 16 + 4 * l4 + i;
      const float inv = __shfl(invl[m], 4 * l4 + i, 64);
#pragma unroll
      for (int n = 0; n < 4; ++n)
        Xb[((size_t)bidx * Sc + q) * Dc + h * DKc + n * 16 + l15] = f2bf(aco[m][n][i] * inv);
    }
}

// ---------------------------------------------------------------------------
extern "C" void kernel_launch(void* const* d_in, const int* in_sizes, int n_in,
                              void* d_out, int out_size, void* d_ws, size_t ws_size,
                              hipStream_t stream) {
  const float* query = (const float*)d_in[0];
  const float* key   = (const float*)d_in[1];
  const float* value = (const float*)d_in[2];
  const float* Wq = (const float*)d_in[4];
  const float* bq = (const float*)d_in[5];
  const float* Wk = (const float*)d_in[6];
  const float* bk = (const float*)d_in[7];
  const float* Wv = (const float*)d_in[8];
  const float* bv = (const float*)d_in[9];
  const float* Wo = (const float*)d_in[10];
  const float* bo = (const float*)d_in[11];

  const size_t MD = (size_t)Mc * Dc;   // 4M
  const size_t DD = (size_t)Dc * Dc;   // 1M
  u16* xq = (u16*)d_ws;
  u16* xk = xq + MD;
  u16* xv = xk + MD;
  u16* wq = xv + MD;
  u16* wk = wq + DD;
  u16* wv = wk + DD;
  u16* wo = wv + DD;
  u16* Qb = wo + DD;
  u16* Kb = Qb + MD;
  u16* Vt = Kb + MD;
  u16* Xb = Vt + MD;   // total 64 MB

  cast_many<<<dim3(MD / 2048, 3), 256, 0, stream>>>(
      query, key, value, nullptr, xq, xk, xv, nullptr, (int)(MD / 8));
  cast_many<<<dim3(DD / 2048, 4), 256, 0, stream>>>(
      Wq, Wk, Wv, Wo, wq, wk, wv, wo, (int)(DD / 8));

  gemm_qkv<<<dim3(Mc / 128, Dc / 128, 3), 512, 0, stream>>>(
      xq, xk, xv, wq, wk, wv, bq, bk, bv, Qb, Kb, Vt);
  attn_mfma<<<dim3(Sc / 128, Bc * Hc), 256, 0, stream>>>(Qb, Kb, Vt, Xb);
  gemm_out<<<dim3(Mc / 128, Dc / 128), 512, 0, stream>>>(Xb, wo, bo, (float*)d_out);
}

// Round 7
// 272.742 us; speedup vs baseline: 1.4040x; 1.4040x over previous
//
#include <hip/hip_runtime.h>
#include <hip/hip_bf16.h>
#include <math.h>

typedef unsigned short u16;
typedef unsigned int u32;
typedef __attribute__((ext_vector_type(4))) float f32x4;
typedef __attribute__((ext_vector_type(4))) short bf16x4;
typedef __attribute__((ext_vector_type(8))) short bf16x8;
typedef __attribute__((ext_vector_type(8))) unsigned short u16x8;

constexpr int Bc = 2, Sc = 2048, Dc = 1024, Hc = 16, DKc = 64, Mc = 4096;

__device__ __forceinline__ u16 f2bf(float f) {
  __hip_bfloat16 h = __float2bfloat16(f);      // RNE, hw v_cvt (pairs to cvt_pk)
  return __builtin_bit_cast(u16, h);
}

__device__ __forceinline__ void gll16(const u16* g, const u16* l) {
  __builtin_amdgcn_global_load_lds((const __attribute__((address_space(1))) void*)g,
                                   (__attribute__((address_space(3))) void*)l, 16, 0, 0);
}

// ---------------------------------------------------------------------------
// LDS tiles are [R rows][64 cols] u16 (128-B rows). XOR swizzle on 16-B slots:
// u16 index ^= ((row & 7) << 3); source side pre-swizzled for global_load_lds
// (rule #21: both-sides-or-neither).
// ---------------------------------------------------------------------------
__device__ __forceinline__ bf16x8 frag_swz(const u16* tile, int row, int col) {
  const int sw = (row & 7) << 3;
  const int base = row * 64 + col;
  bf16x4 lo = *(const bf16x4*)(tile + (base ^ sw));
  bf16x4 hi = *(const bf16x4*)(tile + ((base + 16) ^ sw));
  return __builtin_shufflevector(lo, hi, 0, 1, 2, 3, 4, 5, 6, 7);
}

// ---------------------------------------------------------------------------
__global__ __launch_bounds__(256) void cast_many(
    const float* __restrict__ i0, const float* __restrict__ i1,
    const float* __restrict__ i2, const float* __restrict__ i3,
    u16* __restrict__ o0, u16* __restrict__ o1,
    u16* __restrict__ o2, u16* __restrict__ o3, int n8)
{
  const int z = blockIdx.y;
  const float* in = z == 0 ? i0 : z == 1 ? i1 : z == 2 ? i2 : i3;
  u16* out = z == 0 ? o0 : z == 1 ? o1 : z == 2 ? o2 : o3;
  const int i = blockIdx.x * 256 + threadIdx.x;
  if (i >= n8) return;
  const float4* p = (const float4*)in + (size_t)i * 2;
  const float4 a = p[0], b = p[1];
  u16x8 o;
  o[0] = f2bf(a.x); o[1] = f2bf(a.y); o[2] = f2bf(a.z); o[3] = f2bf(a.w);
  o[4] = f2bf(b.x); o[5] = f2bf(b.y); o[6] = f2bf(b.z); o[7] = f2bf(b.w);
  ((u16x8*)out)[i] = o;
}

// ---------------------------------------------------------------------------
// gemm_core: acc = X[row0:+128] @ W[col0:+128]^T (bf16, BK=64, 512 thr, 4x2
// wave grid, wave tile 32x64, swizzled LDS, global_load_lds dbuf)
// ---------------------------------------------------------------------------
__device__ __forceinline__ void gemm_core(
    const u16* __restrict__ X, const u16* __restrict__ W,
    u16* smem, int row0, int col0, f32x4 (&acc)[2][4])
{
  const int tid = threadIdx.x;
  const int w = tid >> 6, lane = tid & 63;
  const int l15 = lane & 15, l4 = lane >> 4;
  const int wr = w >> 1, wc = w & 1;

  auto stage = [&](int buf, int k0) {
    u16* dA = smem + buf * 8192;
    u16* dB = smem + 16384 + buf * 8192;
#pragma unroll
    for (int s = 0; s < 2; ++s) {
      const int c = s * 512 + w * 64 + lane;
      const int r = c >> 3;
      const int cc = (c & 7) ^ (r & 7);          // pre-swizzled source slot
      gll16(X + (size_t)(row0 + r) * Dc + k0 + cc * 8, dA + (s * 512 + w * 64) * 8);
      gll16(W + (size_t)(col0 + r) * Dc + k0 + cc * 8, dB + (s * 512 + w * 64) * 8);
    }
  };

  stage(0, 0);
  __syncthreads();

  for (int kt = 0; kt < Dc / 64; ++kt) {
    const int cur = kt & 1;
    if (kt + 1 < Dc / 64) stage(cur ^ 1, (kt + 1) * 64);
    const u16* At = smem + cur * 8192;
    const u16* Bt = smem + 16384 + cur * 8192;
#pragma unroll
    for (int ks = 0; ks < 2; ++ks) {
      bf16x8 af[2], bfr[4];
#pragma unroll
      for (int m = 0; m < 2; ++m)
        af[m] = frag_swz(At, wr * 32 + m * 16 + l15, ks * 32 + l4 * 4);
#pragma unroll
      for (int n = 0; n < 4; ++n)
        bfr[n] = frag_swz(Bt, wc * 64 + n * 16 + l15, ks * 32 + l4 * 4);
#pragma unroll
      for (int m = 0; m < 2; ++m)
#pragma unroll
        for (int n = 0; n < 4; ++n)
          acc[m][n] = __builtin_amdgcn_mfma_f32_16x16x32_bf16(af[m], bfr[n], acc[m][n], 0, 0, 0);
    }
    __syncthreads();
  }
}

// ---------------------------------------------------------------------------
// gemm_qkv: fused Q/K/V projections (blockIdx.z). z=0,1 -> RoPE -> [B,H,S,DK];
// z=2 -> V transposed -> [B,H,DK,S].
// ---------------------------------------------------------------------------
__global__ __launch_bounds__(512) void gemm_qkv(
    const u16* __restrict__ xq, const u16* __restrict__ xk, const u16* __restrict__ xv,
    const u16* __restrict__ wq, const u16* __restrict__ wk, const u16* __restrict__ wv,
    const float* __restrict__ bq, const float* __restrict__ bk, const float* __restrict__ bv,
    u16* __restrict__ Qb, u16* __restrict__ Kb, u16* __restrict__ Vt)
{
  __shared__ u16 smem[4 * 128 * 64];             // 64 KB
  const int z = blockIdx.z;
  const u16* X = z == 0 ? xq : z == 1 ? xk : xv;
  const u16* W = z == 0 ? wq : z == 1 ? wk : wv;
  const float* bias = z == 0 ? bq : z == 1 ? bk : bv;

  const int tid = threadIdx.x;
  const int w = tid >> 6, lane = tid & 63;
  const int l15 = lane & 15, l4 = lane >> 4;
  const int wr = w >> 1, wc = w & 1;
  const int row0 = blockIdx.x * 128;
  const int col0 = blockIdx.y * 128;

  f32x4 acc[2][4] = {};
  gemm_core(X, W, smem, row0, col0, acc);

  if (z < 2) {                                   // Q or K: +bias, RoPE
    u16* Out = z == 0 ? Qb : Kb;
    const int h = (col0 >> 6) + wc;
#pragma unroll
    for (int m = 0; m < 2; ++m)
#pragma unroll
      for (int i = 0; i < 4; ++i) {
        const int row = row0 + wr * 32 + m * 16 + 4 * l4 + i;
        const int srow = row & (Sc - 1);
        const size_t obase = ((size_t)((row >> 11) * Hc + h) * Sc + srow) * DKc;
        float vv[4];
#pragma unroll
        for (int n = 0; n < 4; ++n)
          vv[n] = acc[m][n][i] + bias[col0 + wc * 64 + n * 16 + l15];
        float cs[2], sn[2];
#pragma unroll
        for (int hf = 0; hf < 2; ++hf) {
          const int jj = hf * 16 + l15;          // dk & 31
          const float ang = (float)srow * exp2f((float)jj * (-13.287712379549449f / 32.0f));
          sincosf(ang, &sn[hf], &cs[hf]);        // sin FIRST
        }
#pragma unroll
        for (int n = 0; n < 4; ++n) {
          const float rot = (n < 2) ? -vv[n ^ 2] : vv[n ^ 2];   // partner dk^32
          const float o = vv[n] * cs[n & 1] + rot * sn[n & 1];
          Out[obase + n * 16 + l15] = f2bf(o);
        }
      }
  } else {                                       // V -> [B,H,DK,S] via LDS transpose
    u16* T = smem;                               // [128 c][132 r]
    __syncthreads();
#pragma unroll
    for (int m = 0; m < 2; ++m)
#pragma unroll
      for (int i = 0; i < 4; ++i) {
        const int r = wr * 32 + m * 16 + 4 * l4 + i;
#pragma unroll
        for (int n = 0; n < 4; ++n) {
          const int c = wc * 64 + n * 16 + l15;
          T[c * 132 + r] = f2bf(acc[m][n][i] + bias[col0 + c]);
        }
      }
    __syncthreads();
    const int bidx = row0 >> 11, srow0 = row0 & (Sc - 1);
    const int c = tid >> 2, rq = (tid & 3) * 32;
    const int h = (col0 >> 6) + (c >> 6);
    const int dk = c & 63;
    u16* gdst = Vt + ((size_t)(bidx * Hc + h) * DKc + dk) * Sc + srow0 + rq;
#pragma unroll
    for (int u = 0; u < 4; ++u)
      *(u16x8*)(gdst + u * 8) = *(const u16x8*)&T[c * 132 + rq + u * 8];
  }
}

// ---------------------------------------------------------------------------
__global__ __launch_bounds__(512) void gemm_out(
    const u16* __restrict__ X, const u16* __restrict__ W,
    const float* __restrict__ bias, float* __restrict__ Out)
{
  __shared__ u16 smem[4 * 128 * 64];
  const int tid = threadIdx.x;
  const int w = tid >> 6, lane = tid & 63;
  const int l15 = lane & 15, l4 = lane >> 4;
  const int wr = w >> 1, wc = w & 1;
  const int row0 = blockIdx.x * 128;
  const int col0 = blockIdx.y * 128;

  f32x4 acc[2][4] = {};
  gemm_core(X, W, smem, row0, col0, acc);

#pragma unroll
  for (int m = 0; m < 2; ++m)
#pragma unroll
    for (int i = 0; i < 4; ++i) {
      const int row = row0 + wr * 32 + m * 16 + 4 * l4 + i;
#pragma unroll
      for (int n = 0; n < 4; ++n) {
        const int col = col0 + wc * 64 + n * 16 + l15;
        Out[(size_t)row * Dc + col] = acc[m][n][i] + bias[col];
      }
    }
}

// ---------------------------------------------------------------------------
// attn_mfma: causal flash attention, swapped-QK^T in-register softmax.
// QBLK=128 (4 waves x 32 q-rows), KVBLK=64, dbuf K/V staging, swizzled LDS.
// S^T = mfma(K_frag, Q_frag): thread holds S^T[k=n*16+4*l4+i][q=m*16+l15]
// -> row softmax = 15 local ops + 2 shuffles; P^T regs feed PV's A-operand
// directly (n=2ks+(j>>2), i=j&3). No P LDS round-trip.
// O/corr live on q=m*16+4*l4+i rows -> 4-way lane transpose via __shfl.
// NOTE: no min-occupancy in launch_bounds — R6's (256,3) capped the unified
// VGPR/AGPR budget below the ~190-reg live set and spilled to scratch
// (WRITE_SIZE 8->33 MB, VGPR 120->84). Spill-free > occupancy here.
// ---------------------------------------------------------------------------
__global__ __launch_bounds__(256) void attn_mfma(
    const u16* __restrict__ Qb, const u16* __restrict__ Kb,
    const u16* __restrict__ Vt, u16* __restrict__ Xb)
{
  __shared__ u16 smem[24576];                    // 48 KB
  // Qs [128][64] @0; K bufs @8192+buf*4096; V bufs @16384+buf*4096
  u16* Qs = smem;

  const int tid = threadIdx.x;
  const int w = tid >> 6, lane = tid & 63;
  const int l15 = lane & 15, l4 = lane >> 4;
  const int qt = gridDim.x - 1 - blockIdx.x;     // heavy q-tiles first
  const int bh = blockIdx.y;
  const int q0 = qt * 128;
  const u16* Qg = Qb + ((size_t)bh * Sc + q0) * DKc;
  const u16* Kg = Kb + (size_t)bh * Sc * DKc;
  const u16* Vg = Vt + (size_t)bh * DKc * Sc;

  // stage Q (swizzled source)
#pragma unroll
  for (int s = 0; s < 4; ++s) {
    const int c = s * 256 + w * 64 + lane;
    const int r = c >> 3;
    const int cc = (c & 7) ^ (r & 7);
    gll16(Qg + (size_t)r * DKc + cc * 8, Qs + (s * 256 + w * 64) * 8);
  }
  auto stageKV = [&](int buf, int k0) {
    u16* Kd = smem + 8192 + buf * 4096;
    u16* Vd = smem + 16384 + buf * 4096;
#pragma unroll
    for (int s = 0; s < 2; ++s) {
      const int c = s * 256 + w * 64 + lane;
      const int r = c >> 3;
      const int cc = (c & 7) ^ (r & 7);
      gll16(Kg + (size_t)(k0 + r) * DKc + cc * 8, Kd + (s * 256 + w * 64) * 8);
      gll16(Vg + (size_t)r * Sc + k0 + cc * 8,   Vd + (s * 256 + w * 64) * 8);
    }
  };
  stageKV(0, 0);
  __syncthreads();

  // hoist Q fragments (reused across all k-tiles)
  bf16x8 aq[2][2];
#pragma unroll
  for (int m = 0; m < 2; ++m)
#pragma unroll
    for (int ks = 0; ks < 2; ++ks)
      aq[m][ks] = frag_swz(Qs, w * 32 + m * 16 + l15, ks * 32 + l4 * 4);

  f32x4 aco[2][4] = {};
  float mreg[2], lreg[2];
#pragma unroll
  for (int m = 0; m < 2; ++m) { mreg[m] = -INFINITY; lreg[m] = 0.f; }

  const int nk = 2 * qt + 2;
  for (int kt = 0; kt < nk; ++kt) {
    const int cur = kt & 1;
    if (kt + 1 < nk) stageKV(cur ^ 1, (kt + 1) * 64);
    const u16* Kt = smem + 8192 + cur * 4096;
    const u16* Vc = smem + 16384 + cur * 4096;

    // S^T = K Q^T : acs[m][n][i] = S[q=m*16+l15][k=n*16+4*l4+i]
    f32x4 acs[2][4] = {};
#pragma unroll
    for (int ks = 0; ks < 2; ++ks) {
      bf16x8 bk[4];
#pragma unroll
      for (int n = 0; n < 4; ++n)
        bk[n] = frag_swz(Kt, n * 16 + l15, ks * 32 + l4 * 4);
#pragma unroll
      for (int m = 0; m < 2; ++m)
#pragma unroll
        for (int n = 0; n < 4; ++n)
          acs[m][n] = __builtin_amdgcn_mfma_f32_16x16x32_bf16(bk[n], aq[m][ks], acs[m][n], 0, 0, 0);
    }

    // in-register online softmax (q lane-local)
    const bool mtile = (kt >= 2 * qt);
    const int k0 = kt * 64;
    float corr[2];
#pragma unroll
    for (int m = 0; m < 2; ++m) {
      const int q = q0 + w * 32 + m * 16 + l15;
      float rm = -INFINITY;
#pragma unroll
      for (int n = 0; n < 4; ++n)
#pragma unroll
        for (int i = 0; i < 4; ++i) {
          float s = acs[m][n][i] * 0.125f;
          if (mtile && (k0 + n * 16 + 4 * l4 + i) > q) s = -1e9f;
          acs[m][n][i] = s;
          rm = fmaxf(rm, s);
        }
      rm = fmaxf(rm, __shfl_xor(rm, 16, 64));
      rm = fmaxf(rm, __shfl_xor(rm, 32, 64));
      const float mnew = fmaxf(mreg[m], rm);
      corr[m] = __expf(mreg[m] - mnew);
      mreg[m] = mnew;
      float rs = 0.f;
#pragma unroll
      for (int n = 0; n < 4; ++n)
#pragma unroll
        for (int i = 0; i < 4; ++i) {
          const float p = __expf(acs[m][n][i] - mnew);
          acs[m][n][i] = p;
          rs += p;
        }
      rs += __shfl_xor(rs, 16, 64);
      rs += __shfl_xor(rs, 32, 64);
      lreg[m] = lreg[m] * corr[m] + rs;
    }

    // rescale O (rows q=m*16+4*l4+i): fetch corr via lane transpose
#pragma unroll
    for (int m = 0; m < 2; ++m)
#pragma unroll
      for (int i = 0; i < 4; ++i) {
        const float c = __shfl(corr[m], 4 * l4 + i, 64);
#pragma unroll
        for (int n = 0; n < 4; ++n) aco[m][n][i] *= c;
      }

    // pack P^T regs -> PV A-frags (exact layout match)
    bf16x8 pa[2][2];
#pragma unroll
    for (int m = 0; m < 2; ++m)
#pragma unroll
      for (int ks = 0; ks < 2; ++ks) {
        bf16x8 t;
#pragma unroll
        for (int j = 0; j < 8; ++j)
          t[j] = (short)f2bf(acs[m][ks * 2 + (j >> 2)][j & 3]);
        pa[m][ks] = t;
      }

    // O += P V
#pragma unroll
    for (int ks = 0; ks < 2; ++ks) {
      bf16x8 bv[4];
#pragma unroll
      for (int n = 0; n < 4; ++n)
        bv[n] = frag_swz(Vc, n * 16 + l15, ks * 32 + l4 * 4);
#pragma unroll
      for (int m = 0; m < 2; ++m)
#pragma unroll
        for (int n = 0; n < 4; ++n)
          aco[m][n] = __builtin_amdgcn_mfma_f32_16x16x32_bf16(pa[m][ks], bv[n], aco[m][n], 0, 0, 0);
    }
    __syncthreads();
  }

  // epilogue: x[b, q, h*64+dk] = O/l (1/l via lane transpose)
  const int bidx = bh >> 4, h = bh & 15;
  float invl[2];
#pragma unroll
  for (int m = 0; m < 2; ++m) invl[m] = 1.0f / lreg[m];
#pragma unroll
  for (int m = 0; m < 2; ++m)
#pragma unroll
    for (int i = 0; i < 4; ++i) {
      const int q = q0 + w * 32 + m * 16 + 4 * l4 + i;
      const float inv = __shfl(invl[m], 4 * l4 + i, 64);
#pragma unroll
      for (int n = 0; n < 4; ++n)
        Xb[((size_t)bidx * Sc + q) * Dc + h * DKc + n * 16 + l15] = f2bf(aco[m][n][i] * inv);
    }
}

// ---------------------------------------------------------------------------
extern "C" void kernel_launch(void* const* d_in, const int* in_sizes, int n_in,
                              void* d_out, int out_size, void* d_ws, size_t ws_size,
                              hipStream_t stream) {
  const float* query = (const float*)d_in[0];
  const float* key   = (const float*)d_in[1];
  const float* value = (const float*)d_in[2];
  const float* Wq = (const float*)d_in[4];
  const float* bq = (const float*)d_in[5];
  const float* Wk = (const float*)d_in[6];
  const float* bk = (const float*)d_in[7];
  const float* Wv = (const float*)d_in[8];
  const float* bv = (const float*)d_in[9];
  const float* Wo = (const float*)d_in[10];
  const float* bo = (const float*)d_in[11];

  const size_t MD = (size_t)Mc * Dc;   // 4M
  const size_t DD = (size_t)Dc * Dc;   // 1M
  u16* xq = (u16*)d_ws;
  u16* xk = xq + MD;
  u16* xv = xk + MD;
  u16* wq = xv + MD;
  u16* wk = wq + DD;
  u16* wv = wk + DD;
  u16* wo = wv + DD;
  u16* Qb = wo + DD;
  u16* Kb = Qb + MD;
  u16* Vt = Kb + MD;
  u16* Xb = Vt + MD;   // total 64 MB

  cast_many<<<dim3(MD / 2048, 3), 256, 0, stream>>>(
      query, key, value, nullptr, xq, xk, xv, nullptr, (int)(MD / 8));
  cast_many<<<dim3(DD / 2048, 4), 256, 0, stream>>>(
      Wq, Wk, Wv, Wo, wq, wk, wv, wo, (int)(DD / 8));

  gemm_qkv<<<dim3(Mc / 128, Dc / 128, 3), 512, 0, stream>>>(
      xq, xk, xv, wq, wk, wv, bq, bk, bv, Qb, Kb, Vt);
  attn_mfma<<<dim3(Sc / 128, Bc * Hc), 256, 0, stream>>>(Qb, Kb, Vt, Xb);
  gemm_out<<<dim3(Mc / 128, Dc / 128), 512, 0, stream>>>(Xb, wo, bo, (float*)d_out);
}

// Round 8
// 272.228 us; speedup vs baseline: 1.4066x; 1.0019x over previous
//
#include <hip/hip_runtime.h>
#include <hip/hip_bf16.h>
#include <math.h>

typedef unsigned short u16;
typedef unsigned int u32;
typedef __attribute__((ext_vector_type(4))) float f32x4;
typedef __attribute__((ext_vector_type(4))) short bf16x4;
typedef __attribute__((ext_vector_type(8))) short bf16x8;
typedef __attribute__((ext_vector_type(8))) unsigned short u16x8;

constexpr int Bc = 2, Sc = 2048, Dc = 1024, Hc = 16, DKc = 64, Mc = 4096;

__device__ __forceinline__ u16 f2bf(float f) {
  __hip_bfloat16 h = __float2bfloat16(f);      // RNE, hw v_cvt
  return __builtin_bit_cast(u16, h);
}

__device__ __forceinline__ void gll16(const u16* g, const u16* l) {
  __builtin_amdgcn_global_load_lds((const __attribute__((address_space(1))) void*)g,
                                   (__attribute__((address_space(3))) void*)l, 16, 0, 0);
}

// ---------------------------------------------------------------------------
// LDS tiles are [R rows][64 cols] u16 (128-B rows). XOR swizzle on 16-B slots:
// u16 index ^= ((row & 7) << 3); source side pre-swizzled for global_load_lds
// (rule #21: both-sides-or-neither).
// ---------------------------------------------------------------------------
__device__ __forceinline__ bf16x8 frag_swz(const u16* tile, int row, int col) {
  const int sw = (row & 7) << 3;
  const int base = row * 64 + col;
  bf16x4 lo = *(const bf16x4*)(tile + (base ^ sw));
  bf16x4 hi = *(const bf16x4*)(tile + ((base + 16) ^ sw));
  return __builtin_shufflevector(lo, hi, 0, 1, 2, 3, 4, 5, 6, 7);
}

// ---------------------------------------------------------------------------
__global__ __launch_bounds__(256) void cast_many(
    const float* __restrict__ i0, const float* __restrict__ i1,
    const float* __restrict__ i2, const float* __restrict__ i3,
    u16* __restrict__ o0, u16* __restrict__ o1,
    u16* __restrict__ o2, u16* __restrict__ o3, int n8)
{
  const int z = blockIdx.y;
  const float* in = z == 0 ? i0 : z == 1 ? i1 : z == 2 ? i2 : i3;
  u16* out = z == 0 ? o0 : z == 1 ? o1 : z == 2 ? o2 : o3;
  const int i = blockIdx.x * 256 + threadIdx.x;
  if (i >= n8) return;
  const float4* p = (const float4*)in + (size_t)i * 2;
  const float4 a = p[0], b = p[1];
  u16x8 o;
  o[0] = f2bf(a.x); o[1] = f2bf(a.y); o[2] = f2bf(a.z); o[3] = f2bf(a.w);
  o[4] = f2bf(b.x); o[5] = f2bf(b.y); o[6] = f2bf(b.z); o[7] = f2bf(b.w);
  ((u16x8*)out)[i] = o;
}

// ---------------------------------------------------------------------------
// gemm_core: acc = X[row0:+64] @ W[col0:+128]^T (bf16, BK=64, 256 thr = 4
// waves 2x2, wave tile 32x64, swizzled LDS, global_load_lds dbuf).
// 64x128 tile (vs 128x128) doubles grid -> 2-3 blocks/CU co-residency.
// ---------------------------------------------------------------------------
__device__ __forceinline__ void gemm_core(
    const u16* __restrict__ X, const u16* __restrict__ W,
    u16* smem, int row0, int col0, f32x4 (&acc)[2][4])
{
  const int tid = threadIdx.x;
  const int w = tid >> 6, lane = tid & 63;
  const int l15 = lane & 15, l4 = lane >> 4;
  const int wr = w >> 1, wc = w & 1;

  // LDS: A bufs @0 + buf*4096 (64x64), B bufs @8192 + buf*8192 (128x64)
  auto stage = [&](int buf, int k0) {
    u16* dA = smem + buf * 4096;
    u16* dB = smem + 8192 + buf * 8192;
#pragma unroll
    for (int s = 0; s < 2; ++s) {
      const int c = s * 256 + w * 64 + lane;     // A chunk 0..511
      const int r = c >> 3, cc = (c & 7) ^ (r & 7);
      gll16(X + (size_t)(row0 + r) * Dc + k0 + cc * 8, dA + (s * 256 + w * 64) * 8);
    }
#pragma unroll
    for (int s = 0; s < 4; ++s) {
      const int c = s * 256 + w * 64 + lane;     // B chunk 0..1023
      const int r = c >> 3, cc = (c & 7) ^ (r & 7);
      gll16(W + (size_t)(col0 + r) * Dc + k0 + cc * 8, dB + (s * 256 + w * 64) * 8);
    }
  };

  stage(0, 0);
  __syncthreads();

  for (int kt = 0; kt < Dc / 64; ++kt) {
    const int cur = kt & 1;
    if (kt + 1 < Dc / 64) stage(cur ^ 1, (kt + 1) * 64);
    const u16* At = smem + cur * 4096;
    const u16* Bt = smem + 8192 + cur * 8192;
#pragma unroll
    for (int ks = 0; ks < 2; ++ks) {
      bf16x8 af[2], bfr[4];
#pragma unroll
      for (int m = 0; m < 2; ++m)
        af[m] = frag_swz(At, wr * 32 + m * 16 + l15, ks * 32 + l4 * 4);
#pragma unroll
      for (int n = 0; n < 4; ++n)
        bfr[n] = frag_swz(Bt, wc * 64 + n * 16 + l15, ks * 32 + l4 * 4);
#pragma unroll
      for (int m = 0; m < 2; ++m)
#pragma unroll
        for (int n = 0; n < 4; ++n)
          acc[m][n] = __builtin_amdgcn_mfma_f32_16x16x32_bf16(af[m], bfr[n], acc[m][n], 0, 0, 0);
    }
    __syncthreads();
  }
}

// ---------------------------------------------------------------------------
// gemm_qkv: fused Q/K/V projections (blockIdx.z). z=0,1 -> RoPE -> [B,H,S,DK];
// z=2 -> V transposed -> [B,H,DK,S]. Tile 64x128, 256 threads.
// ---------------------------------------------------------------------------
__global__ __launch_bounds__(256) void gemm_qkv(
    const u16* __restrict__ xq, const u16* __restrict__ xk, const u16* __restrict__ xv,
    const u16* __restrict__ wq, const u16* __restrict__ wk, const u16* __restrict__ wv,
    const float* __restrict__ bq, const float* __restrict__ bk, const float* __restrict__ bv,
    u16* __restrict__ Qb, u16* __restrict__ Kb, u16* __restrict__ Vt)
{
  __shared__ u16 smem[24576];                    // 48 KB
  const int z = blockIdx.z;
  const u16* X = z == 0 ? xq : z == 1 ? xk : xv;
  const u16* W = z == 0 ? wq : z == 1 ? wk : wv;
  const float* bias = z == 0 ? bq : z == 1 ? bk : bv;

  const int tid = threadIdx.x;
  const int w = tid >> 6, lane = tid & 63;
  const int l15 = lane & 15, l4 = lane >> 4;
  const int wr = w >> 1, wc = w & 1;
  const int row0 = blockIdx.x * 64;
  const int col0 = blockIdx.y * 128;

  f32x4 acc[2][4] = {};
  gemm_core(X, W, smem, row0, col0, acc);

  if (z < 2) {                                   // Q or K: +bias, RoPE
    u16* Out = z == 0 ? Qb : Kb;
    const int h = (col0 >> 6) + wc;
#pragma unroll
    for (int m = 0; m < 2; ++m)
#pragma unroll
      for (int i = 0; i < 4; ++i) {
        const int row = row0 + wr * 32 + m * 16 + 4 * l4 + i;
        const int srow = row & (Sc - 1);
        const size_t obase = ((size_t)((row >> 11) * Hc + h) * Sc + srow) * DKc;
        float vv[4];
#pragma unroll
        for (int n = 0; n < 4; ++n)
          vv[n] = acc[m][n][i] + bias[col0 + wc * 64 + n * 16 + l15];
        float cs[2], sn[2];
#pragma unroll
        for (int hf = 0; hf < 2; ++hf) {
          const int jj = hf * 16 + l15;          // dk & 31
          const float ang = (float)srow * exp2f((float)jj * (-13.287712379549449f / 32.0f));
          sincosf(ang, &sn[hf], &cs[hf]);        // sin FIRST
        }
#pragma unroll
        for (int n = 0; n < 4; ++n) {
          const float rot = (n < 2) ? -vv[n ^ 2] : vv[n ^ 2];   // partner dk^32
          const float o = vv[n] * cs[n & 1] + rot * sn[n & 1];
          Out[obase + n * 16 + l15] = f2bf(o);
        }
      }
  } else {                                       // V -> [B,H,DK,S] via LDS transpose
    u16* T = smem;                               // [128 c][stride 72 r]
    __syncthreads();
#pragma unroll
    for (int m = 0; m < 2; ++m)
#pragma unroll
      for (int i = 0; i < 4; ++i) {
        const int r = wr * 32 + m * 16 + 4 * l4 + i;
#pragma unroll
        for (int n = 0; n < 4; ++n) {
          const int c = wc * 64 + n * 16 + l15;
          T[c * 72 + r] = f2bf(acc[m][n][i] + bias[col0 + c]);
        }
      }
    __syncthreads();
    const int bidx = row0 >> 11, srow0 = row0 & (Sc - 1);
    const int c = tid >> 1, rq = (tid & 1) * 32;
    const int h = (col0 >> 6) + (c >> 6);
    const int dk = c & 63;
    u16* gdst = Vt + ((size_t)(bidx * Hc + h) * DKc + dk) * Sc + srow0 + rq;
#pragma unroll
    for (int u = 0; u < 4; ++u)
      *(u16x8*)(gdst + u * 8) = *(const u16x8*)&T[c * 72 + rq + u * 8];
  }
}

// ---------------------------------------------------------------------------
__global__ __launch_bounds__(256) void gemm_out(
    const u16* __restrict__ X, const u16* __restrict__ W,
    const float* __restrict__ bias, float* __restrict__ Out)
{
  __shared__ u16 smem[24576];
  const int tid = threadIdx.x;
  const int w = tid >> 6, lane = tid & 63;
  const int l15 = lane & 15, l4 = lane >> 4;
  const int wr = w >> 1, wc = w & 1;
  const int row0 = blockIdx.x * 64;
  const int col0 = blockIdx.y * 128;

  f32x4 acc[2][4] = {};
  gemm_core(X, W, smem, row0, col0, acc);

#pragma unroll
  for (int m = 0; m < 2; ++m)
#pragma unroll
    for (int i = 0; i < 4; ++i) {
      const int row = row0 + wr * 32 + m * 16 + 4 * l4 + i;
#pragma unroll
      for (int n = 0; n < 4; ++n) {
        const int col = col0 + wc * 64 + n * 16 + l15;
        Out[(size_t)row * Dc + col] = acc[m][n][i] + bias[col];
      }
    }
}

// ---------------------------------------------------------------------------
// attn_mfma: causal flash attention, swapped-QK^T in-register softmax.
// QBLK=64 (4 waves x 16 q-rows -> grid 1024 = 4 blocks/CU), KVBLK=64,
// dbuf K/V staging, swizzled LDS. Softmax in exp2 domain (v_exp_f32 is
// exp2 in hw; fold 0.125*log2e into the scale). T13 defer-rescale: skip
// O-rescale when the tile max didn't grow by >8 (exp2-domain).
// S^T = mfma(K_frag, Q_frag): thread holds S^T[k=n*16+4*l4+i][q=w*16+l15];
// P^T regs feed PV's A-operand directly. No P LDS round-trip.
// ---------------------------------------------------------------------------
__global__ __launch_bounds__(256) void attn_mfma(
    const u16* __restrict__ Qb, const u16* __restrict__ Kb,
    const u16* __restrict__ Vt, u16* __restrict__ Xb)
{
  __shared__ u16 smem[20480];                    // 40 KB
  // Qs [64][64] @0; K bufs @4096+buf*4096; V bufs @12288+buf*4096
  u16* Qs = smem;

  const int tid = threadIdx.x;
  const int w = tid >> 6, lane = tid & 63;
  const int l15 = lane & 15, l4 = lane >> 4;
  const int qt = gridDim.x - 1 - blockIdx.x;     // heavy q-tiles first
  const int bh = blockIdx.y;
  const int q0 = qt * 64;
  const u16* Qg = Qb + ((size_t)bh * Sc + q0) * DKc;
  const u16* Kg = Kb + (size_t)bh * Sc * DKc;
  const u16* Vg = Vt + (size_t)bh * DKc * Sc;

  // stage Q (512 chunks, swizzled source)
#pragma unroll
  for (int s = 0; s < 2; ++s) {
    const int c = s * 256 + w * 64 + lane;
    const int r = c >> 3, cc = (c & 7) ^ (r & 7);
    gll16(Qg + (size_t)r * DKc + cc * 8, Qs + (s * 256 + w * 64) * 8);
  }
  auto stageKV = [&](int buf, int k0) {
    u16* Kd = smem + 4096 + buf * 4096;
    u16* Vd = smem + 12288 + buf * 4096;
#pragma unroll
    for (int s = 0; s < 2; ++s) {
      const int c = s * 256 + w * 64 + lane;
      const int r = c >> 3, cc = (c & 7) ^ (r & 7);
      gll16(Kg + (size_t)(k0 + r) * DKc + cc * 8, Kd + (s * 256 + w * 64) * 8);
      gll16(Vg + (size_t)r * Sc + k0 + cc * 8,   Vd + (s * 256 + w * 64) * 8);
    }
  };
  stageKV(0, 0);
  __syncthreads();

  // hoist Q fragments (reused across all k-tiles)
  bf16x8 aq[2];
#pragma unroll
  for (int ks = 0; ks < 2; ++ks)
    aq[ks] = frag_swz(Qs, w * 16 + l15, ks * 32 + l4 * 4);

  f32x4 aco[4] = {};
  float mreg = -INFINITY, lreg = 0.f;
  constexpr float C2 = 0.18033688011112042f;     // 0.125 * log2(e)

  const int nk = qt + 1;
  for (int kt = 0; kt < nk; ++kt) {
    const int cur = kt & 1;
    if (kt + 1 < nk) stageKV(cur ^ 1, (kt + 1) * 64);
    const u16* Kt = smem + 4096 + cur * 4096;
    const u16* Vc = smem + 12288 + cur * 4096;

    // S^T = K Q^T : acs[n][i] = S[q=w*16+l15][k=n*16+4*l4+i]  (exp2 domain)
    f32x4 acs[4] = {};
#pragma unroll
    for (int ks = 0; ks < 2; ++ks) {
      bf16x8 bk[4];
#pragma unroll
      for (int n = 0; n < 4; ++n)
        bk[n] = frag_swz(Kt, n * 16 + l15, ks * 32 + l4 * 4);
#pragma unroll
      for (int n = 0; n < 4; ++n)
        acs[n] = __builtin_amdgcn_mfma_f32_16x16x32_bf16(bk[n], aq[ks], acs[n], 0, 0, 0);
    }

    // in-register online softmax (q lane-local, exp2 domain)
    const bool mtile = (kt == qt);
    const int k0 = kt * 64;
    const int q = q0 + w * 16 + l15;
    float rm = -INFINITY;
#pragma unroll
    for (int n = 0; n < 4; ++n)
#pragma unroll
      for (int i = 0; i < 4; ++i) {
        float s = acs[n][i] * C2;
        if (mtile && (k0 + n * 16 + 4 * l4 + i) > q) s = -1e30f;
        acs[n][i] = s;
        rm = fmaxf(rm, s);
      }
    rm = fmaxf(rm, __shfl_xor(rm, 16, 64));
    rm = fmaxf(rm, __shfl_xor(rm, 32, 64));

    const bool need = __any(rm > mreg + 8.0f);   // T13 defer-rescale vote
    float corr = 1.f;
    if (need) {
      const float mnew = fmaxf(mreg, rm);
      corr = exp2f(mreg - mnew);                 // 0 on first tile
      mreg = mnew;
    }
    float rs = 0.f;
#pragma unroll
    for (int n = 0; n < 4; ++n)
#pragma unroll
      for (int i = 0; i < 4; ++i) {
        const float p = exp2f(acs[n][i] - mreg); // <= 2^8 when deferred
        acs[n][i] = p;
        rs += p;
      }
    rs += __shfl_xor(rs, 16, 64);
    rs += __shfl_xor(rs, 32, 64);
    lreg = lreg * corr + rs;
    if (need) {
#pragma unroll
      for (int i = 0; i < 4; ++i) {
        const float c = __shfl(corr, 4 * l4 + i, 64);
#pragma unroll
        for (int n = 0; n < 4; ++n) aco[n][i] *= c;
      }
    }

    // pack P^T regs -> PV A-frags (exact layout match)
    bf16x8 pa[2];
#pragma unroll
    for (int ks = 0; ks < 2; ++ks) {
      bf16x8 t;
#pragma unroll
      for (int j = 0; j < 8; ++j)
        t[j] = (short)f2bf(acs[ks * 2 + (j >> 2)][j & 3]);
      pa[ks] = t;
    }

    // O += P V
#pragma unroll
    for (int ks = 0; ks < 2; ++ks) {
      bf16x8 bv[4];
#pragma unroll
      for (int n = 0; n < 4; ++n)
        bv[n] = frag_swz(Vc, n * 16 + l15, ks * 32 + l4 * 4);
#pragma unroll
      for (int n = 0; n < 4; ++n)
        aco[n] = __builtin_amdgcn_mfma_f32_16x16x32_bf16(pa[ks], bv[n], aco[n], 0, 0, 0);
    }
    __syncthreads();
  }

  // epilogue: x[b, q, h*64+dk] = O/l (1/l via lane transpose)
  const int bidx = bh >> 4, h = bh & 15;
  const float invl = 1.0f / lreg;
#pragma unroll
  for (int i = 0; i < 4; ++i) {
    const int q = q0 + w * 16 + 4 * l4 + i;
    const float inv = __shfl(invl, 4 * l4 + i, 64);
#pragma unroll
    for (int n = 0; n < 4; ++n)
      Xb[((size_t)bidx * Sc + q) * Dc + h * DKc + n * 16 + l15] = f2bf(aco[n][i] * inv);
  }
}

// ---------------------------------------------------------------------------
extern "C" void kernel_launch(void* const* d_in, const int* in_sizes, int n_in,
                              void* d_out, int out_size, void* d_ws, size_t ws_size,
                              hipStream_t stream) {
  const float* query = (const float*)d_in[0];
  const float* key   = (const float*)d_in[1];
  const float* value = (const float*)d_in[2];
  const float* Wq = (const float*)d_in[4];
  const float* bq = (const float*)d_in[5];
  const float* Wk = (const float*)d_in[6];
  const float* bk = (const float*)d_in[7];
  const float* Wv = (const float*)d_in[8];
  const float* bv = (const float*)d_in[9];
  const float* Wo = (const float*)d_in[10];
  const float* bo = (const float*)d_in[11];

  const size_t MD = (size_t)Mc * Dc;   // 4M
  const size_t DD = (size_t)Dc * Dc;   // 1M
  u16* xq = (u16*)d_ws;
  u16* xk = xq + MD;
  u16* xv = xk + MD;
  u16* wq = xv + MD;
  u16* wk = wq + DD;
  u16* wv = wk + DD;
  u16* wo = wv + DD;
  u16* Qb = wo + DD;
  u16* Kb = Qb + MD;
  u16* Vt = Kb + MD;
  u16* Xb = Vt + MD;   // total 64 MB

  cast_many<<<dim3(MD / 2048, 3), 256, 0, stream>>>(
      query, key, value, nullptr, xq, xk, xv, nullptr, (int)(MD / 8));
  cast_many<<<dim3(DD / 2048, 4), 256, 0, stream>>>(
      Wq, Wk, Wv, Wo, wq, wk, wv, wo, (int)(DD / 8));

  gemm_qkv<<<dim3(Mc / 64, Dc / 128, 3), 256, 0, stream>>>(
      xq, xk, xv, wq, wk, wv, bq, bk, bv, Qb, Kb, Vt);
  attn_mfma<<<dim3(Sc / 64, Bc * Hc), 256, 0, stream>>>(Qb, Kb, Vt, Xb);
  gemm_out<<<dim3(Mc / 64, Dc / 128), 256, 0, stream>>>(Xb, wo, bo, (float*)d_out);
}

// Round 9
// 232.298 us; speedup vs baseline: 1.6484x; 1.1719x over previous
//
#include <hip/hip_runtime.h>
#include <hip/hip_bf16.h>
#include <math.h>

typedef unsigned short u16;
typedef unsigned int u32;
typedef __attribute__((ext_vector_type(4))) float f32x4;
typedef __attribute__((ext_vector_type(4))) short bf16x4;
typedef __attribute__((ext_vector_type(8))) short bf16x8;
typedef __attribute__((ext_vector_type(8))) unsigned short u16x8;

constexpr int Bc = 2, Sc = 2048, Dc = 1024, Hc = 16, DKc = 64, Mc = 4096;

__device__ __forceinline__ u16 f2bf(float f) {
  __hip_bfloat16 h = __float2bfloat16(f);      // RNE, hw v_cvt
  return __builtin_bit_cast(u16, h);
}

__device__ __forceinline__ void gll16(const u16* g, const u16* l) {
  __builtin_amdgcn_global_load_lds((const __attribute__((address_space(1))) void*)g,
                                   (__attribute__((address_space(3))) void*)l, 16, 0, 0);
}

// ---------------------------------------------------------------------------
// LDS tiles are [R rows][64 cols] u16 (128-B rows). XOR swizzle on 16-B slots:
// u16 index ^= ((row & 7) << 3); source side pre-swizzled for global_load_lds
// (rule #21: both-sides-or-neither).
// ---------------------------------------------------------------------------
__device__ __forceinline__ bf16x8 frag_swz(const u16* tile, int row, int col) {
  const int sw = (row & 7) << 3;
  const int base = row * 64 + col;
  bf16x4 lo = *(const bf16x4*)(tile + (base ^ sw));
  bf16x4 hi = *(const bf16x4*)(tile + ((base + 16) ^ sw));
  return __builtin_shufflevector(lo, hi, 0, 1, 2, 3, 4, 5, 6, 7);
}

// ---------------------------------------------------------------------------
__global__ __launch_bounds__(256) void cast_many(
    const float* __restrict__ i0, const float* __restrict__ i1,
    const float* __restrict__ i2, const float* __restrict__ i3,
    u16* __restrict__ o0, u16* __restrict__ o1,
    u16* __restrict__ o2, u16* __restrict__ o3, int n8)
{
  const int z = blockIdx.y;
  const float* in = z == 0 ? i0 : z == 1 ? i1 : z == 2 ? i2 : i3;
  u16* out = z == 0 ? o0 : z == 1 ? o1 : z == 2 ? o2 : o3;
  const int i = blockIdx.x * 256 + threadIdx.x;
  if (i >= n8) return;
  const float4* p = (const float4*)in + (size_t)i * 2;
  const float4 a = p[0], b = p[1];
  u16x8 o;
  o[0] = f2bf(a.x); o[1] = f2bf(a.y); o[2] = f2bf(a.z); o[3] = f2bf(a.w);
  o[4] = f2bf(b.x); o[5] = f2bf(b.y); o[6] = f2bf(b.z); o[7] = f2bf(b.w);
  ((u16x8*)out)[i] = o;
}

// ---------------------------------------------------------------------------
// XCD-aware tile remap (T1): 256 WGs (32x8), dispatch d -> XCD d%8 (round
// robin). XCD x owns bx in {4x..4x+3} x all by: working set = 4 A-slabs
// (1 MB) + all B panels (2 MB) = 3 MB, fits the 4 MB per-XCD L2.
// ---------------------------------------------------------------------------
__device__ __forceinline__ void gemm_remap(int& row0, int& col0) {
  const int flat = blockIdx.x + gridDim.x * blockIdx.y;  // 0..255, x fastest
  const int loc = flat >> 3;
  row0 = ((flat & 7) * 4 + (loc & 3)) * 128;
  col0 = (loc >> 2) * 128;
}

// ---------------------------------------------------------------------------
// gemm_core: acc = X[row0:+128] @ W[col0:+128]^T (bf16, BK=64, 512 thr, 8
// waves 4x2, wave tile 32x64, swizzled LDS, global_load_lds dbuf).
// ---------------------------------------------------------------------------
__device__ __forceinline__ void gemm_core(
    const u16* __restrict__ X, const u16* __restrict__ W,
    u16* smem, int row0, int col0, f32x4 (&acc)[2][4])
{
  const int tid = threadIdx.x;
  const int w = tid >> 6, lane = tid & 63;
  const int l15 = lane & 15, l4 = lane >> 4;
  const int wr = w >> 1, wc = w & 1;

  auto stage = [&](int buf, int k0) {
    u16* dA = smem + buf * 8192;
    u16* dB = smem + 16384 + buf * 8192;
#pragma unroll
    for (int s = 0; s < 2; ++s) {
      const int c = s * 512 + w * 64 + lane;
      const int r = c >> 3;
      const int cc = (c & 7) ^ (r & 7);          // pre-swizzled source slot
      gll16(X + (size_t)(row0 + r) * Dc + k0 + cc * 8, dA + (s * 512 + w * 64) * 8);
      gll16(W + (size_t)(col0 + r) * Dc + k0 + cc * 8, dB + (s * 512 + w * 64) * 8);
    }
  };

  stage(0, 0);
  __syncthreads();

  for (int kt = 0; kt < Dc / 64; ++kt) {
    const int cur = kt & 1;
    if (kt + 1 < Dc / 64) stage(cur ^ 1, (kt + 1) * 64);
    const u16* At = smem + cur * 8192;
    const u16* Bt = smem + 16384 + cur * 8192;
#pragma unroll
    for (int ks = 0; ks < 2; ++ks) {
      bf16x8 af[2], bfr[4];
#pragma unroll
      for (int m = 0; m < 2; ++m)
        af[m] = frag_swz(At, wr * 32 + m * 16 + l15, ks * 32 + l4 * 4);
#pragma unroll
      for (int n = 0; n < 4; ++n)
        bfr[n] = frag_swz(Bt, wc * 64 + n * 16 + l15, ks * 32 + l4 * 4);
#pragma unroll
      for (int m = 0; m < 2; ++m)
#pragma unroll
        for (int n = 0; n < 4; ++n)
          acc[m][n] = __builtin_amdgcn_mfma_f32_16x16x32_bf16(af[m], bfr[n], acc[m][n], 0, 0, 0);
    }
    __syncthreads();
  }
}

// ---------------------------------------------------------------------------
// gemm_qkv: fused Q/K/V projections (blockIdx.z). z=0,1 -> RoPE -> [B,H,S,DK];
// z=2 -> V transposed -> [B,H,DK,S]. Tile 128x128, 512 threads.
// ---------------------------------------------------------------------------
__global__ __launch_bounds__(512) void gemm_qkv(
    const u16* __restrict__ xq, const u16* __restrict__ xk, const u16* __restrict__ xv,
    const u16* __restrict__ wq, const u16* __restrict__ wk, const u16* __restrict__ wv,
    const float* __restrict__ bq, const float* __restrict__ bk, const float* __restrict__ bv,
    u16* __restrict__ Qb, u16* __restrict__ Kb, u16* __restrict__ Vt)
{
  __shared__ u16 smem[4 * 128 * 64];             // 64 KB
  const int z = blockIdx.z;
  const u16* X = z == 0 ? xq : z == 1 ? xk : xv;
  const u16* W = z == 0 ? wq : z == 1 ? wk : wv;
  const float* bias = z == 0 ? bq : z == 1 ? bk : bv;

  const int tid = threadIdx.x;
  const int w = tid >> 6, lane = tid & 63;
  const int l15 = lane & 15, l4 = lane >> 4;
  const int wr = w >> 1, wc = w & 1;
  int row0, col0;
  gemm_remap(row0, col0);

  f32x4 acc[2][4] = {};
  gemm_core(X, W, smem, row0, col0, acc);

  if (z < 2) {                                   // Q or K: +bias, RoPE
    u16* Out = z == 0 ? Qb : Kb;
    const int h = (col0 >> 6) + wc;
#pragma unroll
    for (int m = 0; m < 2; ++m)
#pragma unroll
      for (int i = 0; i < 4; ++i) {
        const int row = row0 + wr * 32 + m * 16 + 4 * l4 + i;
        const int srow = row & (Sc - 1);
        const size_t obase = ((size_t)((row >> 11) * Hc + h) * Sc + srow) * DKc;
        float vv[4];
#pragma unroll
        for (int n = 0; n < 4; ++n)
          vv[n] = acc[m][n][i] + bias[col0 + wc * 64 + n * 16 + l15];
        float cs[2], sn[2];
#pragma unroll
        for (int hf = 0; hf < 2; ++hf) {
          const int jj = hf * 16 + l15;          // dk & 31
          const float ang = (float)srow * exp2f((float)jj * (-13.287712379549449f / 32.0f));
          sincosf(ang, &sn[hf], &cs[hf]);        // sin FIRST
        }
#pragma unroll
        for (int n = 0; n < 4; ++n) {
          const float rot = (n < 2) ? -vv[n ^ 2] : vv[n ^ 2];   // partner dk^32
          const float o = vv[n] * cs[n & 1] + rot * sn[n & 1];
          Out[obase + n * 16 + l15] = f2bf(o);
        }
      }
  } else {                                       // V -> [B,H,DK,S] via LDS transpose
    u16* T = smem;                               // [128 c][132 r]
    __syncthreads();
#pragma unroll
    for (int m = 0; m < 2; ++m)
#pragma unroll
      for (int i = 0; i < 4; ++i) {
        const int r = wr * 32 + m * 16 + 4 * l4 + i;
#pragma unroll
        for (int n = 0; n < 4; ++n) {
          const int c = wc * 64 + n * 16 + l15;
          T[c * 132 + r] = f2bf(acc[m][n][i] + bias[col0 + c]);
        }
      }
    __syncthreads();
    const int bidx = row0 >> 11, srow0 = row0 & (Sc - 1);
    const int c = tid >> 2, rq = (tid & 3) * 32;
    const int h = (col0 >> 6) + (c >> 6);
    const int dk = c & 63;
    u16* gdst = Vt + ((size_t)(bidx * Hc + h) * DKc + dk) * Sc + srow0 + rq;
#pragma unroll
    for (int u = 0; u < 4; ++u)
      *(u16x8*)(gdst + u * 8) = *(const u16x8*)&T[c * 132 + rq + u * 8];
  }
}

// ---------------------------------------------------------------------------
__global__ __launch_bounds__(512) void gemm_out(
    const u16* __restrict__ X, const u16* __restrict__ W,
    const float* __restrict__ bias, float* __restrict__ Out)
{
  __shared__ u16 smem[4 * 128 * 64];
  const int tid = threadIdx.x;
  const int w = tid >> 6, lane = tid & 63;
  const int l15 = lane & 15, l4 = lane >> 4;
  const int wr = w >> 1, wc = w & 1;
  int row0, col0;
  gemm_remap(row0, col0);

  f32x4 acc[2][4] = {};
  gemm_core(X, W, smem, row0, col0, acc);

#pragma unroll
  for (int m = 0; m < 2; ++m)
#pragma unroll
    for (int i = 0; i < 4; ++i) {
      const int row = row0 + wr * 32 + m * 16 + 4 * l4 + i;
#pragma unroll
      for (int n = 0; n < 4; ++n) {
        const int col = col0 + wc * 64 + n * 16 + l15;
        Out[(size_t)row * Dc + col] = acc[m][n][i] + bias[col];
      }
    }
}

// ---------------------------------------------------------------------------
// attn_mfma: causal flash attention, swapped-QK^T in-register softmax,
// 2-deep software pipeline (T15): QK^T(t+1) issued BEFORE softmax(t) so the
// MFMA+ds_read stream overlaps the softmax VALU chain. K/V tri-buffered
// (stage t+2 in flight || QK reads t+1 || PV reads t); the Q staging region
// is dead after the register hoist and is recycled as K-buffer 2 -> 48 KB,
// 3 blocks/CU. XCD remap: each XCD owns 4 heads (4 MB K/V = one L2).
// QBLK=64 (4 waves x 16 q-rows), KVBLK=64. exp2-domain softmax + T13
// defer-rescale. No P LDS round-trip.
// ---------------------------------------------------------------------------
__global__ __launch_bounds__(256) void attn_mfma(
    const u16* __restrict__ Qb, const u16* __restrict__ Kb,
    const u16* __restrict__ Vt, u16* __restrict__ Xb)
{
  __shared__ u16 smem[24576];                    // 48 KB
  // K bufs @ {0, 8192, 16384}; V bufs @ {4096, 12288, 20480}; Qs @ 16384
  // (K buf 2 == Qs region, first written only after all waves hoisted Q).
  u16* Qs = smem + 16384;

  const int tid = threadIdx.x;
  const int w = tid >> 6, lane = tid & 63;
  const int l15 = lane & 15, l4 = lane >> 4;

  // XCD remap: dispatch d -> XCD d%8; XCD x gets bh in {4x..4x+3} (all qt).
  const int d = blockIdx.x + gridDim.x * blockIdx.y;   // 0..1023
  const int loc = d >> 3;
  const int bh = (d & 7) * 4 + (loc & 3);
  const int qt = 31 - (loc >> 2);                // heavy q-tiles first
  const int q0 = qt * 64;
  const u16* Qg = Qb + ((size_t)bh * Sc + q0) * DKc;
  const u16* Kg = Kb + (size_t)bh * Sc * DKc;
  const u16* Vg = Vt + (size_t)bh * DKc * Sc;
  const int nk = qt + 1;

  // stage Q (512 chunks, swizzled source)
#pragma unroll
  for (int s = 0; s < 2; ++s) {
    const int c = s * 256 + tid;
    const int r = c >> 3, cc = (c & 7) ^ (r & 7);
    gll16(Qg + (size_t)r * DKc + cc * 8, Qs + c * 8);
  }
  auto stageKV = [&](int buf, int k0) {
    u16* Kd = smem + (buf == 0 ? 0 : buf == 1 ? 8192 : 16384);
    u16* Vd = smem + (buf == 0 ? 4096 : buf == 1 ? 12288 : 20480);
#pragma unroll
    for (int s = 0; s < 2; ++s) {
      const int c = s * 256 + tid;
      const int r = c >> 3, cc = (c & 7) ^ (r & 7);
      gll16(Kg + (size_t)(k0 + r) * DKc + cc * 8, Kd + c * 8);
      gll16(Vg + (size_t)r * Sc + k0 + cc * 8,   Vd + c * 8);
    }
  };
  stageKV(0, 0);
  __syncthreads();                               // Q + buf0 ready

  // hoist Q fragments (Qs region is dead after this; recycled as K buf 2)
  bf16x8 aq[2];
#pragma unroll
  for (int ks = 0; ks < 2; ++ks)
    aq[ks] = frag_swz(Qs, w * 16 + l15, ks * 32 + l4 * 4);

  if (nk > 1) stageKV(1, 64);                    // in flight across iter 0

  auto QK = [&](f32x4 (&dst)[4], int buf) {
    const u16* Kt = smem + (buf == 0 ? 0 : buf == 1 ? 8192 : 16384);
#pragma unroll
    for (int ks = 0; ks < 2; ++ks) {
      bf16x8 bk[4];
#pragma unroll
      for (int n = 0; n < 4; ++n)
        bk[n] = frag_swz(Kt, n * 16 + l15, ks * 32 + l4 * 4);
#pragma unroll
      for (int n = 0; n < 4; ++n)
        dst[n] = __builtin_amdgcn_mfma_f32_16x16x32_bf16(bk[n], aq[ks], dst[n], 0, 0, 0);
    }
  };

  f32x4 sA[4] = {}, sB[4] = {};
  QK(sA, 0);                                     // scores for tile 0

  f32x4 aco[4] = {};
  float mreg = -INFINITY, lreg = 0.f;
  constexpr float C2 = 0.18033688011112042f;     // 0.125 * log2(e)

  auto ITER = [&](int t, f32x4 (&cur)[4], f32x4 (&nxt)[4]) {
    __syncthreads();                             // stage(t+1) landed; all waves past QK(t)
    const int tb = t - (t / 3) * 3;              // t % 3
    if (t + 2 < nk) stageKV(tb + 2 >= 3 ? tb - 1 : tb + 2, (t + 2) * 64);
    if (t + 1 < nk) {                            // QK(t+1): overlaps softmax(t)
#pragma unroll
      for (int n = 0; n < 4; ++n) nxt[n] = f32x4{0.f, 0.f, 0.f, 0.f};
      QK(nxt, tb + 1 >= 3 ? tb - 2 : tb + 1);
    }

    // softmax(t) on cur (q lane-local, exp2 domain)
    const bool mtile = (t == nk - 1);
    const int k0t = t * 64;
    const int q = q0 + w * 16 + l15;
    float rm = -INFINITY;
#pragma unroll
    for (int n = 0; n < 4; ++n)
#pragma unroll
      for (int i = 0; i < 4; ++i) {
        float s = cur[n][i] * C2;
        if (mtile && (k0t + n * 16 + 4 * l4 + i) > q) s = -1e30f;
        cur[n][i] = s;
        rm = fmaxf(rm, s);
      }
    rm = fmaxf(rm, __shfl_xor(rm, 16, 64));
    rm = fmaxf(rm, __shfl_xor(rm, 32, 64));

    const bool need = __any(rm > mreg + 8.0f);   // T13 defer-rescale vote
    float corr = 1.f;
    if (need) {
      const float mnew = fmaxf(mreg, rm);
      corr = exp2f(mreg - mnew);
      mreg = mnew;
    }
    float rs = 0.f;
#pragma unroll
    for (int n = 0; n < 4; ++n)
#pragma unroll
      for (int i = 0; i < 4; ++i) {
        const float p = exp2f(cur[n][i] - mreg);
        cur[n][i] = p;
        rs += p;
      }
    rs += __shfl_xor(rs, 16, 64);
    rs += __shfl_xor(rs, 32, 64);
    lreg = lreg * corr + rs;
    if (need) {
#pragma unroll
      for (int i = 0; i < 4; ++i) {
        const float c = __shfl(corr, 4 * l4 + i, 64);
#pragma unroll
        for (int n = 0; n < 4; ++n) aco[n][i] *= c;
      }
    }

    // pack P^T regs -> PV A-frags (exact layout match)
    bf16x8 pa[2];
#pragma unroll
    for (int ks = 0; ks < 2; ++ks) {
      bf16x8 tt;
#pragma unroll
      for (int j = 0; j < 8; ++j)
        tt[j] = (short)f2bf(cur[ks * 2 + (j >> 2)][j & 3]);
      pa[ks] = tt;
    }

    // O += P V  (V buf t%3)
    const u16* Vc = smem + (tb == 0 ? 4096 : tb == 1 ? 12288 : 20480);
#pragma unroll
    for (int ks = 0; ks < 2; ++ks) {
      bf16x8 bv[4];
#pragma unroll
      for (int n = 0; n < 4; ++n)
        bv[n] = frag_swz(Vc, n * 16 + l15, ks * 32 + l4 * 4);
#pragma unroll
      for (int n = 0; n < 4; ++n)
        aco[n] = __builtin_amdgcn_mfma_f32_16x16x32_bf16(pa[ks], bv[n], aco[n], 0, 0, 0);
    }
  };

  int t = 0;
  while (true) {
    ITER(t, sA, sB);
    if (++t >= nk) break;
    ITER(t, sB, sA);
    if (++t >= nk) break;
  }

  // epilogue: x[b, q, h*64+dk] = O/l (1/l via lane transpose)
  const int bidx = bh >> 4, h = bh & 15;
  const float invl = 1.0f / lreg;
#pragma unroll
  for (int i = 0; i < 4; ++i) {
    const int q = q0 + w * 16 + 4 * l4 + i;
    const float inv = __shfl(invl, 4 * l4 + i, 64);
#pragma unroll
    for (int n = 0; n < 4; ++n)
      Xb[((size_t)bidx * Sc + q) * Dc + h * DKc + n * 16 + l15] = f2bf(aco[n][i] * inv);
  }
}

// ---------------------------------------------------------------------------
extern "C" void kernel_launch(void* const* d_in, const int* in_sizes, int n_in,
                              void* d_out, int out_size, void* d_ws, size_t ws_size,
                              hipStream_t stream) {
  const float* query = (const float*)d_in[0];
  const float* key   = (const float*)d_in[1];
  const float* value = (const float*)d_in[2];
  const float* Wq = (const float*)d_in[4];
  const float* bq = (const float*)d_in[5];
  const float* Wk = (const float*)d_in[6];
  const float* bk = (const float*)d_in[7];
  const float* Wv = (const float*)d_in[8];
  const float* bv = (const float*)d_in[9];
  const float* Wo = (const float*)d_in[10];
  const float* bo = (const float*)d_in[11];

  const size_t MD = (size_t)Mc * Dc;   // 4M
  const size_t DD = (size_t)Dc * Dc;   // 1M
  u16* xq = (u16*)d_ws;
  u16* xk = xq + MD;
  u16* xv = xk + MD;
  u16* wq = xv + MD;
  u16* wk = wq + DD;
  u16* wv = wk + DD;
  u16* wo = wv + DD;
  u16* Qb = wo + DD;
  u16* Kb = Qb + MD;
  u16* Vt = Kb + MD;
  u16* Xb = Vt + MD;   // total 64 MB

  cast_many<<<dim3(MD / 2048, 3), 256, 0, stream>>>(
      query, key, value, nullptr, xq, xk, xv, nullptr, (int)(MD / 8));
  cast_many<<<dim3(DD / 2048, 4), 256, 0, stream>>>(
      Wq, Wk, Wv, Wo, wq, wk, wv, wo, (int)(DD / 8));

  gemm_qkv<<<dim3(32, 8, 3), 512, 0, stream>>>(
      xq, xk, xv, wq, wk, wv, bq, bk, bv, Qb, Kb, Vt);
  attn_mfma<<<dim3(32, 32), 256, 0, stream>>>(Qb, Kb, Vt, Xb);
  gemm_out<<<dim3(32, 8), 512, 0, stream>>>(Xb, wo, bo, (float*)d_out);
}